// Round 1
// baseline (373.218 us; speedup 1.0000x reference)
//
#include <hip/hip_runtime.h>
#include <math.h>

#define BCOL 64
#define ED 512
#define NROWS 2048
#define RG 4   // rows per softmax-tile group

// Pass A: per-wave online softmax over a chunk of rows of one column.
// v2: 4-row groups with ping-pong prefetch (8 KB/wave in flight, 4x the MLP
// of v1), 4-way-ILP butterfly reduces, and ONE rescale/exp chain per group
// (flash-attention tile update) instead of per row.
__global__ void attn_partial_kernel(const float* __restrict__ emb,
                                    const float* __restrict__ W,
                                    float* __restrict__ accbuf,
                                    float* __restrict__ mbuf,
                                    float* __restrict__ lbuf,
                                    int G, int rowsPerWave)
{
    const int tid  = threadIdx.x;
    const int lane = tid & 63;
    const int wv   = tid >> 6;           // wave within block [0,4)
    const int blk  = blockIdx.x;
    const int col  = blk % BCOL;         // batch column b
    const int chunk = blk / BCOL;        // chunk of rows
    const int g = chunk * 4 + wv;        // partial id within column [0,G)
    const int n0 = g * rowsPerWave;
    const int nGroups = rowsPerWave / RG;   // even for all G in {4..64}

    // W_e = W[512:1024]; preload this wave's 8 weights per lane
    const float4* We4 = (const float4*)(W + 512);
    const float4 w0 = We4[lane];
    const float4 w1 = We4[lane + 64];

    // lane-resolved base for row n0; row k is base4[k * rstride]
    const float4* base4 =
        (const float4*)(emb + ((size_t)n0 * BCOL + col) * ED) + lane;
    const int rstride = BCOL * ED / 4;   // float4 stride between rows (n)

    float m = -INFINITY, l = 0.0f;
    float4 acc0 = {0.f, 0.f, 0.f, 0.f};
    float4 acc1 = {0.f, 0.f, 0.f, 0.f};

    float4 eA[RG], eB[RG], oA[RG], oB[RG];   // ping-pong group buffers

    // preload group 0
    #pragma unroll
    for (int r = 0; r < RG; ++r) {
        eA[r] = base4[(size_t)r * rstride];
        eB[r] = base4[(size_t)r * rstride + 64];
    }

    auto process = [&](float4 (&cA)[RG], float4 (&cB)[RG],
                       float4 (&nA)[RG], float4 (&nB)[RG], int grp) {
        // issue next group's 8 loads FIRST (8 KB in flight during compute)
        if (grp + 1 < nGroups) {
            const int nb = (grp + 1) * RG;
            #pragma unroll
            for (int r = 0; r < RG; ++r) {
                nA[r] = base4[(size_t)(nb + r) * rstride];
                nB[r] = base4[(size_t)(nb + r) * rstride + 64];
            }
        }
        // 4 independent dots
        float p[RG];
        #pragma unroll
        for (int r = 0; r < RG; ++r) {
            p[r] = cA[r].x * w0.x + cA[r].y * w0.y + cA[r].z * w0.z + cA[r].w * w0.w
                 + cB[r].x * w1.x + cB[r].y * w1.y + cB[r].z * w1.z + cB[r].w * w1.w;
        }
        // batched 64-lane butterfly reduce+broadcast: 4-way ILP per stage so
        // the ds_bpermute latency overlaps across rows instead of chaining.
        #pragma unroll
        for (int off = 32; off > 0; off >>= 1) {
            float q[RG];
            #pragma unroll
            for (int r = 0; r < RG; ++r) q[r] = __shfl_xor(p[r], off, 64);
            #pragma unroll
            for (int r = 0; r < RG; ++r) p[r] += q[r];
        }
        // one online-softmax rescale per group (flash-attn tile update)
        const float gmax = fmaxf(fmaxf(p[0], p[1]), fmaxf(p[2], p[3]));
        const float mn   = fmaxf(m, gmax);
        const float corr = __expf(m - mn);   // exp(-inf)=0 on first group
        float pe[RG];
        #pragma unroll
        for (int r = 0; r < RG; ++r) pe[r] = __expf(p[r] - mn);
        l = l * corr + (pe[0] + pe[1] + pe[2] + pe[3]);
        m = mn;
        #define ACC_UPD(A, C, f) \
            A.f = fmaf(pe[3], C[3].f, fmaf(pe[2], C[2].f, \
                  fmaf(pe[1], C[1].f, fmaf(pe[0], C[0].f, A.f * corr))))
        ACC_UPD(acc0, cA, x); ACC_UPD(acc0, cA, y);
        ACC_UPD(acc0, cA, z); ACC_UPD(acc0, cA, w);
        ACC_UPD(acc1, cB, x); ACC_UPD(acc1, cB, y);
        ACC_UPD(acc1, cB, z); ACC_UPD(acc1, cB, w);
        #undef ACC_UPD
    };

    for (int grp = 0; grp < nGroups; grp += 2) {
        process(eA, eB, oA, oB, grp);
        process(oA, oB, eA, eB, grp + 1);
    }

    float4* out4 = (float4*)(accbuf + ((size_t)col * G + g) * ED);
    out4[lane]      = acc0;
    out4[lane + 64] = acc1;
    if (lane == 0) {
        mbuf[col * G + g] = m;
        lbuf[col * G + g] = l;
    }
}

// Pass B: combine G partials per column. v2: 256 blocks (1/CU) of 256
// threads; block = (column, 128-elem quarter); the two thread-halves split
// the G range and the gg loop is unrolled 8-deep for MLP. accbuf is
// L2/L3-resident right after pass A, so this is latency-, not BW-, limited.
__global__ void attn_reduce_kernel(const float* __restrict__ accbuf,
                                   const float* __restrict__ mbuf,
                                   const float* __restrict__ lbuf,
                                   float* __restrict__ out,
                                   int G)
{
    const int b   = blockIdx.x >> 2;     // column
    const int q   = blockIdx.x & 3;      // 128-elem quarter of ED
    const int tid = threadIdx.x;

    __shared__ float sc[64];
    __shared__ float part[128];

    if (tid < 64) {  // wave 0 computes the combine scales
        float mg = (tid < G) ? mbuf[b * G + tid] : -INFINITY;
        float lg = (tid < G) ? lbuf[b * G + tid] : 0.0f;
        float M = mg;
        #pragma unroll
        for (int off = 32; off > 0; off >>= 1)
            M = fmaxf(M, __shfl_xor(M, off, 64));
        float el = lg * __expf(mg - M);
        float L = el;
        #pragma unroll
        for (int off = 32; off > 0; off >>= 1)
            L += __shfl_xor(L, off, 64);
        sc[tid] = __expf(mg - M) / L;
    }
    __syncthreads();

    const int e  = q * 128 + (tid & 127);
    const int h  = tid >> 7;             // which half of the G range
    const int g0 = h * (G >> 1);
    const int gn = G >> 1;
    const float* src = accbuf + (size_t)b * G * ED + e;

    float s = 0.0f;
    #pragma unroll 8
    for (int i = 0; i < gn; ++i)
        s += sc[g0 + i] * src[(size_t)(g0 + i) * ED];

    if (h) part[tid & 127] = s;
    __syncthreads();
    if (!h) out[(size_t)b * ED + e] = s + part[tid + 128 - 128 + 128 - 128 + 0 + 0] + 0.0f * part[0], 
            out[(size_t)b * ED + e] = s + part[tid];
}

extern "C" void kernel_launch(void* const* d_in, const int* in_sizes, int n_in,
                              void* d_out, int out_size, void* d_ws, size_t ws_size,
                              hipStream_t stream) {
    // inputs: 0=state_tm1 (unused: cancels in softmax), 1=embeddings,
    //         2=W (1024), 3=b (unused: cancels)
    const float* emb = (const float*)d_in[1];
    const float* W   = (const float*)d_in[2];
    float* out = (float*)d_out;

    // choose partials-per-column G to fit workspace (prefer 64 = 16 waves/CU)
    int G = 64;
    while (G > 4) {
        size_t need = (size_t)BCOL * G * ED * sizeof(float)
                    + 2 * (size_t)BCOL * G * sizeof(float);
        if (need <= ws_size) break;
        G >>= 1;
    }
    const int rowsPerWave = NROWS / G;

    float* accbuf = (float*)d_ws;
    float* mbuf = accbuf + (size_t)BCOL * G * ED;
    float* lbuf = mbuf + BCOL * G;

    attn_partial_kernel<<<dim3(BCOL * (G / 4)), dim3(256), 0, stream>>>(
        emb, W, accbuf, mbuf, lbuf, G, rowsPerWave);
    attn_reduce_kernel<<<dim3(BCOL * 4), dim3(256), 0, stream>>>(
        accbuf, mbuf, lbuf, out, G);
}